// Round 6
// baseline (267.384 us; speedup 1.0000x reference)
//
#include <hip/hip_runtime.h>
#include <hip/hip_bf16.h>

#define BT 128   // B*T
#define NN 256   // nodes
#define FF 128   // features
#define HH 4     // heads
#define DD 32    // head dim
#define XK 136   // LDS k-stride (bf16): 272B, 16B-aligned, spreads bank groups
#define WCS 264  // LDS col-stride (bf16) for whc: 528B
#define NB (BT * HH)  // cooperative grid: 512 blocks = 2/CU on 256 CUs
#define L2E 1.4426950408889634f

typedef __attribute__((ext_vector_type(8))) short bf16x8;
typedef __attribute__((ext_vector_type(4))) float f32x4;
typedef unsigned int uint;
typedef unsigned short ushort;

__device__ __forceinline__ float elu1(float x) { return x > 0.f ? x : (__expf(x) - 1.f); }
__device__ __forceinline__ float exp2_fast(float x) {
  float r; asm("v_exp_f32 %0, %1" : "=v"(r) : "v"(x)); return r;
}
__device__ __forceinline__ ushort f2bfn(float f) {
  __hip_bfloat16 h = __float2bfloat16(f);
  return *reinterpret_cast<ushort*>(&h);
}
__device__ __forceinline__ float bf2f(ushort u) {
  union { uint u; float f; } v; v.u = ((uint)u) << 16; return v.f;
}
__device__ __forceinline__ uint pk2(float a, float b) {  // -> v_cvt_pk_bf16_f32
  return (uint)f2bfn(a) | ((uint)f2bfn(b) << 16);
}

struct __align__(16) SharedMem {
  ushort xchunk[64 * XK];  // 17.4 KB
  ushort wt[DD * XK];      // 8.7 KB
  ushort whc[DD * WCS];    // 16.9 KB
  float s1s[NN];
  float s2c[NN];
  int jmap[NN];
  int rrankS[NN];
  float redm[4];
  int wcnt[4];
};  // ~47 KB -> 2 blocks/CU

// Device-scope grid barrier (cooperative launch guarantees co-residency).
// Release: __syncthreads drains vmcnt (stores in L2), threadfence writes back
// to the shared L3; acquire: acquire-load + threadfence invalidates local caches.
__device__ __forceinline__ void grid_barrier(uint* cnt, uint* gen) {
  __syncthreads();
  if (threadIdx.x == 0) {
    uint g = __hip_atomic_load(gen, __ATOMIC_RELAXED, __HIP_MEMORY_SCOPE_AGENT);
    __threadfence();
    uint a = __hip_atomic_fetch_add(cnt, 1u, __ATOMIC_ACQ_REL, __HIP_MEMORY_SCOPE_AGENT);
    if (a + 1u == (uint)NB) {
      __hip_atomic_store(cnt, 0u, __ATOMIC_RELAXED, __HIP_MEMORY_SCOPE_AGENT);
      __hip_atomic_fetch_add(gen, 1u, __ATOMIC_ACQ_REL, __HIP_MEMORY_SCOPE_AGENT);
    } else {
      while (__hip_atomic_load(gen, __ATOMIC_ACQUIRE, __HIP_MEMORY_SCOPE_AGENT) == g)
        __builtin_amdgcn_s_sleep(2);
    }
    __threadfence();
  }
  __syncthreads();
}

// One GAT layer for (bt, head): GEMM over compact rows (scores fused into the
// MFMA epilogue via butterfly shfl), rank-1 P in registers, PV MFMA, residual+ELU.
template<bool L0F>
__device__ __forceinline__ void do_layer(
    SharedMem& sm, int bt, int h, int jv,
    const float* __restrict__ xin, const ushort* __restrict__ xprev,
    const float* __restrict__ W, const float* __restrict__ av,
    ushort* __restrict__ xg) {
  const int tid = threadIdx.x;
  const int lane = tid & 63;
  const int w = tid >> 6;
  const int la = lane & 15, lg = lane >> 4;
  const int jv16 = (jv + 15) & ~15;
  const int ntiles = jv16 >> 4;
  const int jvp64 = (jv16 + 63) & ~63;
  const int njb = jvp64 >> 6;

  // stage wt[n][k] = W[k][h*32+n] (bf16, packed k-pairs)
  {
    const int n = tid & 31;
    const int p0 = (tid >> 5) * 8;
    #pragma unroll
    for (int p = 0; p < 8; ++p) {
      int k = (p0 + p) * 2;
      *(uint*)&sm.wt[n * XK + k] =
          pk2(W[k * FF + h * DD + n], W[(k + 1) * FF + h * DD + n]);
    }
  }
  __syncthreads();  // wt + (caller's jmap/pads) ready

  bf16x8 bfr[2][4];
  #pragma unroll
  for (int ct = 0; ct < 2; ++ct)
    #pragma unroll
    for (int ks = 0; ks < 4; ++ks)
      bfr[ct][ks] = *(const bf16x8*)&sm.wt[(ct * 16 + la) * XK + ks * 32 + lg * 8];
  const float a1a = av[la], a1b = av[16 + la];
  const float a2a = av[32 + la], a2b = av[48 + la];

  // ---- GEMM chunks; whc[d][c] transposed write + scores from accumulators ----
  for (int cb = 0; cb < jv16; cb += 64) {
    {
      const int r0 = tid >> 4;
      const int c0 = (tid & 15) * 8;
      #pragma unroll
      for (int it = 0; it < 4; ++it) {
        int r = r0 + it * 16;
        int g = cb + r;
        if (g < jv) {
          if (L0F) {
            const float* xp = xin + ((size_t)bt * NN + sm.jmap[g]) * FF + c0;
            float4 v0 = *(const float4*)xp;
            float4 v1 = *(const float4*)(xp + 4);
            uint4 qq;
            qq.x = pk2(v0.x, v0.y); qq.y = pk2(v0.z, v0.w);
            qq.z = pk2(v1.x, v1.y); qq.w = pk2(v1.z, v1.w);
            *(uint4*)&sm.xchunk[r * XK + c0] = qq;
          } else {
            *(uint4*)&sm.xchunk[r * XK + c0] =
                *(const uint4*)&xprev[((size_t)bt * NN + g) * FF + c0];
          }
        } else if (g < jv16) {
          uint4 z = {0, 0, 0, 0};
          *(uint4*)&sm.xchunk[r * XK + c0] = z;
        }
      }
    }
    __syncthreads();
    if (w * 16 < jv16 - cb) {
      f32x4 acc0 = {}, acc1 = {};
      #pragma unroll
      for (int ks = 0; ks < 4; ++ks) {
        bf16x8 af = *(const bf16x8*)&sm.xchunk[(w * 16 + la) * XK + ks * 32 + lg * 8];
        acc0 = __builtin_amdgcn_mfma_f32_16x16x32_bf16(af, bfr[0][ks], acc0, 0, 0, 0);
        acc1 = __builtin_amdgcn_mfma_f32_16x16x32_bf16(af, bfr[1][ks], acc1, 0, 0, 0);
      }
      #pragma unroll
      for (int reg = 0; reg < 4; ++reg) {
        int c = cb + w * 16 + lg * 4 + reg;
        sm.whc[la * WCS + c]        = f2bfn(acc0[reg]);
        sm.whc[(16 + la) * WCS + c] = f2bfn(acc1[reg]);
        // fp32 scores: s = acc . a_slice, butterfly-reduced over the 16 la-lanes
        float p1 = fmaf(acc0[reg], a1a, acc1[reg] * a1b);
        float p2 = fmaf(acc0[reg], a2a, acc1[reg] * a2b);
        #pragma unroll
        for (int off = 1; off < 16; off <<= 1) {
          p1 += __shfl_xor(p1, off);
          p2 += __shfl_xor(p2, off);
        }
        if (la == reg) {
          sm.s1s[c] = p1 * L2E;
          sm.s2c[c] = (c < jv) ? p2 * L2E : -2e9f;  // pad rows -> p = 0 exactly
        }
      }
    }
    __syncthreads();
  }

  // ---- block max of valid s2 ----
  {
    float m = (tid < jv) ? sm.s2c[tid] : -1e30f;
    #pragma unroll
    for (int off = 32; off > 0; off >>= 1) m = fmaxf(m, __shfl_xor(m, off));
    if (lane == 0) sm.redm[w] = m;
  }
  __syncthreads();
  const float s2max = fmaxf(fmaxf(sm.redm[0], sm.redm[1]), fmaxf(sm.redm[2], sm.redm[3]));

  // ---- PV: wave w owns tiles ti = mi*4 + w; P generated in registers ----
  float s1r[4], em[4];
  #pragma unroll
  for (int mi = 0; mi < 4; ++mi) {
    float s1v = sm.s1s[(mi * 4 + w) * 16 + la];
    s1r[mi] = s1v;
    float t = s1v + s2max;
    em[mi] = fmaxf(t, 0.2f * t);  // exact row max (lrelu monotone)
  }
  f32x4 acc[4][2] = {};
  float den[4] = {0.f, 0.f, 0.f, 0.f};
  for (int jb = 0; jb < njb; ++jb) {
    #pragma unroll
    for (int ks = 0; ks < 2; ++ks) {
      const int j0 = jb * 64 + ks * 32 + lg * 8;
      float4 sa = *(const float4*)&sm.s2c[j0];
      float4 sb = *(const float4*)&sm.s2c[j0 + 4];
      bf16x8 b0 = *(const bf16x8*)&sm.whc[la * WCS + j0];
      bf16x8 b1 = *(const bf16x8*)&sm.whc[(16 + la) * WCS + j0];
      #pragma unroll
      for (int mi = 0; mi < 4; ++mi) {
        if (mi * 4 + w < ntiles) {  // wave-uniform
          const float s1v = s1r[mi], emv = em[mi];
          float t0 = s1v + sa.x, t1 = s1v + sa.y, t2 = s1v + sa.z, t3 = s1v + sa.w;
          float t4 = s1v + sb.x, t5 = s1v + sb.y, t6 = s1v + sb.z, t7 = s1v + sb.w;
          float p0 = exp2_fast(fmaxf(t0, 0.2f * t0) - emv);
          float p1 = exp2_fast(fmaxf(t1, 0.2f * t1) - emv);
          float p2 = exp2_fast(fmaxf(t2, 0.2f * t2) - emv);
          float p3 = exp2_fast(fmaxf(t3, 0.2f * t3) - emv);
          float p4 = exp2_fast(fmaxf(t4, 0.2f * t4) - emv);
          float p5 = exp2_fast(fmaxf(t5, 0.2f * t5) - emv);
          float p6 = exp2_fast(fmaxf(t6, 0.2f * t6) - emv);
          float p7 = exp2_fast(fmaxf(t7, 0.2f * t7) - emv);
          den[mi] += ((p0 + p1) + (p2 + p3)) + ((p4 + p5) + (p6 + p7));
          union { uint4 q; bf16x8 v; } u;
          u.q.x = pk2(p0, p1); u.q.y = pk2(p2, p3);
          u.q.z = pk2(p4, p5); u.q.w = pk2(p6, p7);
          acc[mi][0] = __builtin_amdgcn_mfma_f32_16x16x32_bf16(u.v, b0, acc[mi][0], 0, 0, 0);
          acc[mi][1] = __builtin_amdgcn_mfma_f32_16x16x32_bf16(u.v, b1, acc[mi][1], 0, 0, 0);
        }
      }
    }
  }
  #pragma unroll
  for (int mi = 0; mi < 4; ++mi) {
    den[mi] += __shfl_xor(den[mi], 16);
    den[mi] += __shfl_xor(den[mi], 32);
  }

  // ---- epilogue: residual + ELU -> compact bf16 xg ----
  #pragma unroll
  for (int mi = 0; mi < 4; ++mi) {
    const int ti = mi * 4 + w;
    if (ti < ntiles) {
      const float inv = 1.f / den[mi];  // valid row => p_self > 0
      #pragma unroll
      for (int reg = 0; reg < 4; ++reg) {
        const float invr = __shfl(inv, lg * 4 + reg);
        const int c2 = ti * 16 + lg * 4 + reg;
        if (c2 < jv) {
          #pragma unroll
          for (int nt = 0; nt < 2; ++nt) {
            const int f = h * DD + nt * 16 + la;
            float resid;
            if (L0F) resid = xin[((size_t)bt * NN + sm.jmap[c2]) * FF + f];
            else     resid = bf2f(xprev[((size_t)bt * NN + c2) * FF + f]);
            float v = elu1(resid + acc[mi][nt][reg] * invr);
            xg[((size_t)bt * NN + c2) * FF + f] = f2bfn(v);
          }
        }
      }
    }
  }
}

__global__ __launch_bounds__(256) void fused_coop(
    const float* __restrict__ xin, const int* __restrict__ mask,
    const float* __restrict__ W0, const float* __restrict__ a0,
    const float* __restrict__ W1, const float* __restrict__ a1,
    const float* __restrict__ gam, const float* __restrict__ bet,
    ushort* __restrict__ xg0, ushort* __restrict__ xg1,
    float* __restrict__ out, uint* __restrict__ bar) {
  __shared__ SharedMem sm;
  const int bt = blockIdx.x >> 2;
  const int h = blockIdx.x & 3;
  const int tid = threadIdx.x;
  const int lane = tid & 63;
  const int w = tid >> 6;
  uint* cnt = bar;
  uint* gen = bar + 16;  // separate 64B line

  // ---- phase A: ballot compaction (mask is layer/head-invariant) ----
  const int mv = mask[bt * NN + tid] > 0;
  unsigned long long bal = __ballot(mv);
  if (lane == 0) sm.wcnt[w] = __popcll(bal);
  __syncthreads();
  int base = 0;
  #pragma unroll
  for (int ww = 0; ww < 4; ++ww) if (ww < w) base += sm.wcnt[ww];
  const int jv = sm.wcnt[0] + sm.wcnt[1] + sm.wcnt[2] + sm.wcnt[3];
  const int rk = mv ? base + __popcll(bal & ((1ull << lane) - 1ull)) : -1;
  if (mv) sm.jmap[rk] = tid;
  sm.rrankS[tid] = rk;
  {
    const int jv16 = (jv + 15) & ~15;
    const int jvp64 = (jv16 + 63) & ~63;
    if (tid >= jv16 && tid < jvp64) {  // whc pad cols: zeros (0 * p=0, no NaN)
      #pragma unroll
      for (int d = 0; d < DD; ++d) sm.whc[d * WCS + tid] = 0;
    }
    if (tid >= jv) sm.s2c[tid] = -2e9f;  // pad s2: p = 0 exactly
  }
  // (do_layer's first __syncthreads orders jmap/pads before use)

  do_layer<true>(sm, bt, h, jv, xin, nullptr, W0, a0, xg0);
  grid_barrier(cnt, gen);
  do_layer<false>(sm, bt, h, jv, nullptr, xg0, W1, a1, xg1);
  grid_barrier(cnt, gen);

  // ---- LN + scatter: this block handles nodes [h*64, h*64+64) of bt ----
  {
    const int node = h * 64 + (tid >> 2);
    const int fb = (tid & 3) * 32;
    const int rk2 = sm.rrankS[node];
    float* op = out + ((size_t)bt * NN + node) * FF + fb;
    if (rk2 < 0) {
      float4 z = {0.f, 0.f, 0.f, 0.f};
      #pragma unroll
      for (int i = 0; i < 8; ++i) *(float4*)&op[i * 4] = z;
    } else {
      const ushort* xr = xg1 + ((size_t)bt * NN + rk2) * FF + fb;
      float f[32];
      #pragma unroll
      for (int i = 0; i < 4; ++i) {
        uint4 u = *(const uint4*)&xr[i * 8];
        const uint* pu = (const uint*)&u;
        #pragma unroll
        for (int e = 0; e < 4; ++e) {
          f[i * 8 + e * 2]     = bf2f((ushort)(pu[e] & 0xffffu));
          f[i * 8 + e * 2 + 1] = bf2f((ushort)(pu[e] >> 16));
        }
      }
      float sum = 0.f, sq = 0.f;
      #pragma unroll
      for (int i = 0; i < 32; ++i) { sum += f[i]; sq = fmaf(f[i], f[i], sq); }
      sum += __shfl_xor(sum, 1); sq += __shfl_xor(sq, 1);
      sum += __shfl_xor(sum, 2); sq += __shfl_xor(sq, 2);
      const float mu = sum * (1.f / FF);
      const float var = sq * (1.f / FF) - mu * mu;
      const float rstd = rsqrtf(var + 1e-5f);
      #pragma unroll
      for (int i = 0; i < 8; ++i) {
        float4 g = *(const float4*)&gam[fb + i * 4];
        float4 b = *(const float4*)&bet[fb + i * 4];
        float4 o;
        o.x = (f[i * 4]     - mu) * rstd * g.x + b.x;
        o.y = (f[i * 4 + 1] - mu) * rstd * g.y + b.y;
        o.z = (f[i * 4 + 2] - mu) * rstd * g.z + b.z;
        o.w = (f[i * 4 + 3] - mu) * rstd * g.w + b.w;
        *(float4*)&op[i * 4] = o;
      }
    }
  }
}

// ================= fallback path (round-5 3-kernel), used only if the
// cooperative enqueue is rejected at API level =================
template<bool L0F>
__global__ __launch_bounds__(256) void layer_kernel_fb(
    const float* __restrict__ xin, const ushort* __restrict__ xprev,
    const int* __restrict__ mask, const float* __restrict__ W,
    const float* __restrict__ av, ushort* __restrict__ xg,
    int* __restrict__ rrank_g) {
  __shared__ SharedMem sm;
  const int bt = blockIdx.x >> 2;
  const int h = blockIdx.x & 3;
  const int tid = threadIdx.x;
  const int lane = tid & 63;
  const int w = tid >> 6;
  const int mv = mask[bt * NN + tid] > 0;
  unsigned long long bal = __ballot(mv);
  if (lane == 0) sm.wcnt[w] = __popcll(bal);
  __syncthreads();
  int base = 0;
  #pragma unroll
  for (int ww = 0; ww < 4; ++ww) if (ww < w) base += sm.wcnt[ww];
  const int jv = sm.wcnt[0] + sm.wcnt[1] + sm.wcnt[2] + sm.wcnt[3];
  const int rk = mv ? base + __popcll(bal & ((1ull << lane) - 1ull)) : -1;
  if (mv) sm.jmap[rk] = tid;
  if (L0F && h == 0) rrank_g[bt * NN + tid] = rk;
  {
    const int jv16 = (jv + 15) & ~15;
    const int jvp64 = (jv16 + 63) & ~63;
    if (tid >= jv16 && tid < jvp64) {
      #pragma unroll
      for (int d = 0; d < DD; ++d) sm.whc[d * WCS + tid] = 0;
    }
    if (tid >= jv) sm.s2c[tid] = -2e9f;
  }
  do_layer<L0F>(sm, bt, h, jv, xin, xprev, W, av, xg);
}

__global__ __launch_bounds__(256) void ln_scatter_fb(
    const ushort* __restrict__ xg1, const int* __restrict__ rrank_g,
    const float* __restrict__ gam, const float* __restrict__ bet,
    float* __restrict__ out) {
  const int bt = blockIdx.x >> 2;
  const int q = blockIdx.x & 3;
  const int node = q * 64 + (threadIdx.x >> 2);
  const int fb = (threadIdx.x & 3) * 32;
  const int rk = rrank_g[bt * NN + node];
  float* op = out + ((size_t)bt * NN + node) * FF + fb;
  if (rk < 0) {
    float4 z = {0.f, 0.f, 0.f, 0.f};
    #pragma unroll
    for (int i = 0; i < 8; ++i) *(float4*)&op[i * 4] = z;
  } else {
    const ushort* xr = xg1 + ((size_t)bt * NN + rk) * FF + fb;
    float f[32];
    #pragma unroll
    for (int i = 0; i < 4; ++i) {
      uint4 u = *(const uint4*)&xr[i * 8];
      const uint* pu = (const uint*)&u;
      #pragma unroll
      for (int e = 0; e < 4; ++e) {
        f[i * 8 + e * 2]     = bf2f((ushort)(pu[e] & 0xffffu));
        f[i * 8 + e * 2 + 1] = bf2f((ushort)(pu[e] >> 16));
      }
    }
    float sum = 0.f, sq = 0.f;
    #pragma unroll
    for (int i = 0; i < 32; ++i) { sum += f[i]; sq = fmaf(f[i], f[i], sq); }
    sum += __shfl_xor(sum, 1); sq += __shfl_xor(sq, 1);
    sum += __shfl_xor(sum, 2); sq += __shfl_xor(sq, 2);
    const float mu = sum * (1.f / FF);
    const float var = sq * (1.f / FF) - mu * mu;
    const float rstd = rsqrtf(var + 1e-5f);
    #pragma unroll
    for (int i = 0; i < 8; ++i) {
      float4 g = *(const float4*)&gam[fb + i * 4];
      float4 b = *(const float4*)&bet[fb + i * 4];
      float4 o;
      o.x = (f[i * 4]     - mu) * rstd * g.x + b.x;
      o.y = (f[i * 4 + 1] - mu) * rstd * g.y + b.y;
      o.z = (f[i * 4 + 2] - mu) * rstd * g.z + b.z;
      o.w = (f[i * 4 + 3] - mu) * rstd * g.w + b.w;
      *(float4*)&op[i * 4] = o;
    }
  }
}

extern "C" void kernel_launch(void* const* d_in, const int* in_sizes, int n_in,
                              void* d_out, int out_size, void* d_ws, size_t ws_size,
                              hipStream_t stream) {
  const float* xin   = (const float*)d_in[0];
  const int*   mask  = (const int*)d_in[1];
  const float* W0    = (const float*)d_in[2];
  const float* a0    = (const float*)d_in[3];
  const float* W1    = (const float*)d_in[4];
  const float* a1    = (const float*)d_in[5];
  const float* gamma = (const float*)d_in[6];
  const float* beta  = (const float*)d_in[7];
  float* outp = (float*)d_out;

  ushort* xg0 = (ushort*)d_ws;                       // 8.39 MB compact bf16
  ushort* xg1 = xg0 + (size_t)BT * NN * FF;          // 8.39 MB compact bf16
  uint* bar = (uint*)((char*)d_ws + (size_t)32 * 1024 * 1024);  // barrier state
  int* rrank_g = (int*)((char*)d_ws + (size_t)33 * 1024 * 1024);

  hipMemsetAsync(bar, 0, 256, stream);  // cnt/gen = 0 each call (deterministic)

  void* args[] = {(void*)&xin, (void*)&mask, (void*)&W0, (void*)&a0,
                  (void*)&W1, (void*)&a1, (void*)&gamma, (void*)&beta,
                  (void*)&xg0, (void*)&xg1, (void*)&outp, (void*)&bar};
  hipError_t err = hipLaunchCooperativeKernel(
      (const void*)fused_coop, dim3(NB), dim3(256), args, 0, stream);
  if (err != hipSuccess) {
    // fallback: 3-launch path (identical math)
    layer_kernel_fb<true><<<NB, 256, 0, stream>>>(xin, nullptr, mask, W0, a0, xg0, rrank_g);
    layer_kernel_fb<false><<<NB, 256, 0, stream>>>(nullptr, xg0, mask, W1, a1, xg1, nullptr);
    ln_scatter_fb<<<BT * 4, 256, 0, stream>>>(xg1, rrank_g, gamma, beta, outp);
  }
}

// Round 7
// 48.196 us; speedup vs baseline: 5.5478x; 5.5478x over previous
//
#include <hip/hip_runtime.h>
#include <hip/hip_bf16.h>

#define BT 128   // B*T
#define NN 256   // nodes
#define FF 128   // features
#define HH 4     // heads
#define DD 32    // head dim
#define XK 136   // LDS k-stride (bf16): 272B, 16B-aligned
#define WCS 264  // LDS col-stride (bf16) for whc: 528B
#define L2E 1.4426950408889634f

typedef __attribute__((ext_vector_type(8))) short bf16x8;
typedef __attribute__((ext_vector_type(4))) float f32x4;
typedef unsigned int uint;
typedef unsigned short ushort;

__device__ __forceinline__ float elu1(float x) { return x > 0.f ? x : (__expf(x) - 1.f); }
__device__ __forceinline__ float exp2_fast(float x) {
  float r; asm("v_exp_f32 %0, %1" : "=v"(r) : "v"(x)); return r;
}
__device__ __forceinline__ ushort f2bfn(float f) {
  __hip_bfloat16 h = __float2bfloat16(f);
  return *reinterpret_cast<ushort*>(&h);
}
__device__ __forceinline__ float bf2f(ushort u) {
  union { uint u; float f; } v; v.u = ((uint)u) << 16; return v.f;
}
__device__ __forceinline__ uint pk2(float a, float b) {  // -> v_cvt_pk_bf16_f32
  return (uint)f2bfn(a) | ((uint)f2bfn(b) << 16);
}

// Block = (bt, head). 3 barriers total. A-fragments straight from global
// (no x LDS staging); scores fused into GEMM epilogue via butterfly shfl;
// rank-1 P in registers; PV MFMA; fused residual+ELU -> compact bf16 xg.
template<bool L0F>
__global__ __launch_bounds__(256, 3) void layer_kernel(
    const float* __restrict__ xin, const ushort* __restrict__ xprev,
    const int* __restrict__ mask, const float* __restrict__ W,
    const float* __restrict__ av, ushort* __restrict__ xg,
    int* __restrict__ rrank_g) {
  __shared__ __align__(16) ushort wt[DD * XK];    // 8.7 KB
  __shared__ __align__(16) ushort whc[DD * WCS];  // 16.9 KB
  __shared__ __align__(16) float s1s[NN];
  __shared__ __align__(16) float s2c[NN];
  __shared__ int jmap[NN];
  __shared__ int wcnt[4];

  const int bt = blockIdx.x >> 2;
  const int h = blockIdx.x & 3;
  const int tid = threadIdx.x;
  const int lane = tid & 63;
  const int w = tid >> 6;
  const int la = lane & 15, lg = lane >> 4;

  // ---- ballot compaction ----
  const int mv = mask[bt * NN + tid] > 0;
  unsigned long long bal = __ballot(mv);
  if (lane == 0) wcnt[w] = __popcll(bal);
  __syncthreads();  // #1
  int base = 0;
  #pragma unroll
  for (int ww = 0; ww < 4; ++ww) if (ww < w) base += wcnt[ww];
  const int jv = wcnt[0] + wcnt[1] + wcnt[2] + wcnt[3];
  const int rk = mv ? base + __popcll(bal & ((1ull << lane) - 1ull)) : -1;
  if (mv) jmap[rk] = tid;
  if (L0F && h == 0) rrank_g[bt * NN + tid] = rk;

  const int jv16 = (jv + 15) & ~15;
  const int ntiles = jv16 >> 4;
  const int jvp64 = (jv16 + 63) & ~63;
  const int njb = jvp64 >> 6;

  if (tid >= jv) { s2c[tid] = -2e9f; s1s[tid] = 0.f; }  // pads: p=0 exactly
  if (tid >= jv16 && tid < jvp64) {
    #pragma unroll
    for (int d = 0; d < DD; ++d) whc[d * WCS + tid] = 0;
  }
  // stage wt[n][k] = W[k][h*32+n], uint4 writes (floor-optimal banks)
  {
    const int n = tid & 31;
    #pragma unroll
    for (int it = 0; it < 2; ++it) {
      const int k0 = ((tid >> 5) + it * 8) * 8;
      float wv[8];
      #pragma unroll
      for (int p = 0; p < 8; ++p) wv[p] = W[(k0 + p) * FF + h * DD + n];
      uint4 q;
      q.x = pk2(wv[0], wv[1]); q.y = pk2(wv[2], wv[3]);
      q.z = pk2(wv[4], wv[5]); q.w = pk2(wv[6], wv[7]);
      *(uint4*)&wt[n * XK + k0] = q;
    }
  }
  __syncthreads();  // #2: jmap, wt, pads ready

  bf16x8 bfr[2][4];
  #pragma unroll
  for (int ct = 0; ct < 2; ++ct)
    #pragma unroll
    for (int ks = 0; ks < 4; ++ks)
      bfr[ct][ks] = *(const bf16x8*)&wt[(ct * 16 + la) * XK + ks * 32 + lg * 8];
  const float a1a = av[la], a1b = av[16 + la];
  const float a2a = av[32 + la], a2b = av[48 + la];

  // ---- GEMM: per-wave 16-row tiles, A direct from global, fused scores ----
  for (int rt = w; rt < ntiles; rt += 4) {
    const int r = rt * 16 + la;
    const int src = (r < jv) ? (L0F ? jmap[r] : r) : 0;  // clamp: no OOB
    bf16x8 af[4];
    if (L0F) {
      const float* xp = xin + ((size_t)bt * NN + src) * FF;
      #pragma unroll
      for (int ks = 0; ks < 4; ++ks) {
        float4 v0 = *(const float4*)&xp[ks * 32 + lg * 8];
        float4 v1 = *(const float4*)&xp[ks * 32 + lg * 8 + 4];
        union { uint4 q; bf16x8 v; } u;
        u.q.x = pk2(v0.x, v0.y); u.q.y = pk2(v0.z, v0.w);
        u.q.z = pk2(v1.x, v1.y); u.q.w = pk2(v1.z, v1.w);
        af[ks] = u.v;
      }
    } else {
      const ushort* xp = xprev + ((size_t)bt * NN + src) * FF;
      #pragma unroll
      for (int ks = 0; ks < 4; ++ks)
        af[ks] = *(const bf16x8*)&xp[ks * 32 + lg * 8];
    }
    if (r >= jv) {  // zero pad rows -> whc pad cols exactly 0 (no NaN risk)
      bf16x8 zz = {0, 0, 0, 0, 0, 0, 0, 0};
      #pragma unroll
      for (int ks = 0; ks < 4; ++ks) af[ks] = zz;
    }
    f32x4 acc0 = {}, acc1 = {};
    #pragma unroll
    for (int ks = 0; ks < 4; ++ks) {
      acc0 = __builtin_amdgcn_mfma_f32_16x16x32_bf16(af[ks], bfr[0][ks], acc0, 0, 0, 0);
      acc1 = __builtin_amdgcn_mfma_f32_16x16x32_bf16(af[ks], bfr[1][ks], acc1, 0, 0, 0);
    }
    // whc transposed write: row d = la / 16+la, col c = rt*16 + lg*4 + reg
    {
      uint2 pa, pb;
      pa.x = pk2(acc0[0], acc0[1]); pa.y = pk2(acc0[2], acc0[3]);
      pb.x = pk2(acc1[0], acc1[1]); pb.y = pk2(acc1[2], acc1[3]);
      *(uint2*)&whc[la * WCS + rt * 16 + lg * 4] = pa;
      *(uint2*)&whc[(16 + la) * WCS + rt * 16 + lg * 4] = pb;
    }
    // fp32 scores butterfly-reduced over the 16 la-lanes
    #pragma unroll
    for (int reg = 0; reg < 4; ++reg) {
      float sc1 = fmaf(acc0[reg], a1a, acc1[reg] * a1b);
      float sc2 = fmaf(acc0[reg], a2a, acc1[reg] * a2b);
      #pragma unroll
      for (int off = 1; off < 16; off <<= 1) {
        sc1 += __shfl_xor(sc1, off);
        sc2 += __shfl_xor(sc2, off);
      }
      if (la == reg) {
        const int c = rt * 16 + lg * 4 + reg;
        s1s[c] = sc1 * L2E;
        s2c[c] = (c < jv) ? sc2 * L2E : -2e9f;
      }
    }
  }
  __syncthreads();  // #3: whc, s1s, s2c complete

  // ---- s2max: per-wave reduce over all 256 entries (no extra barrier) ----
  float m = fmaxf(fmaxf(s2c[lane], s2c[64 + lane]),
                  fmaxf(s2c[128 + lane], s2c[192 + lane]));
  #pragma unroll
  for (int off = 32; off > 0; off >>= 1) m = fmaxf(m, __shfl_xor(m, off));
  const float s2max = m;

  // ---- PV: wave w owns tiles ti = mi*4 + w; P generated in registers ----
  float s1r[4], em[4];
  #pragma unroll
  for (int mi = 0; mi < 4; ++mi) {
    float s1v = s1s[(mi * 4 + w) * 16 + la];
    s1r[mi] = s1v;
    float t = s1v + s2max;
    em[mi] = fmaxf(t, 0.2f * t);  // exact row max (lrelu monotone)
  }
  f32x4 acc[4][2] = {};
  float den[4] = {0.f, 0.f, 0.f, 0.f};
  for (int jb = 0; jb < njb; ++jb) {
    #pragma unroll
    for (int ks = 0; ks < 2; ++ks) {
      const int j0 = jb * 64 + ks * 32 + lg * 8;
      float4 sa = *(const float4*)&s2c[j0];
      float4 sb = *(const float4*)&s2c[j0 + 4];
      bf16x8 b0 = *(const bf16x8*)&whc[la * WCS + j0];
      bf16x8 b1 = *(const bf16x8*)&whc[(16 + la) * WCS + j0];
      #pragma unroll
      for (int mi = 0; mi < 4; ++mi) {
        if (mi * 4 + w < ntiles) {  // wave-uniform
          const float s1v = s1r[mi], emv = em[mi];
          float t0 = s1v + sa.x, t1 = s1v + sa.y, t2 = s1v + sa.z, t3 = s1v + sa.w;
          float t4 = s1v + sb.x, t5 = s1v + sb.y, t6 = s1v + sb.z, t7 = s1v + sb.w;
          float p0 = exp2_fast(fmaxf(t0, 0.2f * t0) - emv);
          float p1 = exp2_fast(fmaxf(t1, 0.2f * t1) - emv);
          float p2 = exp2_fast(fmaxf(t2, 0.2f * t2) - emv);
          float p3 = exp2_fast(fmaxf(t3, 0.2f * t3) - emv);
          float p4 = exp2_fast(fmaxf(t4, 0.2f * t4) - emv);
          float p5 = exp2_fast(fmaxf(t5, 0.2f * t5) - emv);
          float p6 = exp2_fast(fmaxf(t6, 0.2f * t6) - emv);
          float p7 = exp2_fast(fmaxf(t7, 0.2f * t7) - emv);
          den[mi] += ((p0 + p1) + (p2 + p3)) + ((p4 + p5) + (p6 + p7));
          union { uint4 q; bf16x8 v; } u;
          u.q.x = pk2(p0, p1); u.q.y = pk2(p2, p3);
          u.q.z = pk2(p4, p5); u.q.w = pk2(p6, p7);
          acc[mi][0] = __builtin_amdgcn_mfma_f32_16x16x32_bf16(u.v, b0, acc[mi][0], 0, 0, 0);
          acc[mi][1] = __builtin_amdgcn_mfma_f32_16x16x32_bf16(u.v, b1, acc[mi][1], 0, 0, 0);
        }
      }
    }
  }
  #pragma unroll
  for (int mi = 0; mi < 4; ++mi) {
    den[mi] += __shfl_xor(den[mi], 16);
    den[mi] += __shfl_xor(den[mi], 32);
  }

  // ---- epilogue: residual + ELU -> compact bf16 xg ----
  #pragma unroll
  for (int mi = 0; mi < 4; ++mi) {
    const int ti = mi * 4 + w;
    if (ti < ntiles) {
      const float inv = 1.f / den[mi];  // valid row => p_self > 0
      #pragma unroll
      for (int reg = 0; reg < 4; ++reg) {
        const float invr = __shfl(inv, lg * 4 + reg);
        const int c2 = ti * 16 + lg * 4 + reg;
        if (c2 < jv) {
          #pragma unroll
          for (int nt = 0; nt < 2; ++nt) {
            const int f = h * DD + nt * 16 + la;
            float resid;
            if (L0F) resid = xin[((size_t)bt * NN + jmap[c2]) * FF + f];
            else     resid = bf2f(xprev[((size_t)bt * NN + c2) * FF + f]);
            float v = elu1(resid + acc[mi][nt][reg] * invr);
            xg[((size_t)bt * NN + c2) * FF + f] = f2bfn(v);
          }
        }
      }
    }
  }
}

// Block = (bt, node-quarter). 4 lanes per node row (32 features each).
__global__ __launch_bounds__(256) void ln_scatter(
    const ushort* __restrict__ xg1, const int* __restrict__ rrank_g,
    const float* __restrict__ gam, const float* __restrict__ bet,
    float* __restrict__ out) {
  const int bt = blockIdx.x >> 2;
  const int q = blockIdx.x & 3;
  const int node = q * 64 + (threadIdx.x >> 2);
  const int fb = (threadIdx.x & 3) * 32;
  const int rk = rrank_g[bt * NN + node];
  float* op = out + ((size_t)bt * NN + node) * FF + fb;
  if (rk < 0) {
    float4 z = {0.f, 0.f, 0.f, 0.f};
    #pragma unroll
    for (int i = 0; i < 8; ++i) *(float4*)&op[i * 4] = z;
  } else {
    const ushort* xr = xg1 + ((size_t)bt * NN + rk) * FF + fb;
    float f[32];
    #pragma unroll
    for (int i = 0; i < 4; ++i) {
      uint4 u = *(const uint4*)&xr[i * 8];
      const uint* pu = (const uint*)&u;
      #pragma unroll
      for (int e = 0; e < 4; ++e) {
        f[i * 8 + e * 2]     = bf2f((ushort)(pu[e] & 0xffffu));
        f[i * 8 + e * 2 + 1] = bf2f((ushort)(pu[e] >> 16));
      }
    }
    float sum = 0.f, sq = 0.f;
    #pragma unroll
    for (int i = 0; i < 32; ++i) { sum += f[i]; sq = fmaf(f[i], f[i], sq); }
    sum += __shfl_xor(sum, 1); sq += __shfl_xor(sq, 1);
    sum += __shfl_xor(sum, 2); sq += __shfl_xor(sq, 2);
    const float mu = sum * (1.f / FF);
    const float var = sq * (1.f / FF) - mu * mu;
    const float rstd = rsqrtf(var + 1e-5f);
    #pragma unroll
    for (int i = 0; i < 8; ++i) {
      float4 g = *(const float4*)&gam[fb + i * 4];
      float4 b = *(const float4*)&bet[fb + i * 4];
      float4 o;
      o.x = (f[i * 4]     - mu) * rstd * g.x + b.x;
      o.y = (f[i * 4 + 1] - mu) * rstd * g.y + b.y;
      o.z = (f[i * 4 + 2] - mu) * rstd * g.z + b.z;
      o.w = (f[i * 4 + 3] - mu) * rstd * g.w + b.w;
      *(float4*)&op[i * 4] = o;
    }
  }
}

extern "C" void kernel_launch(void* const* d_in, const int* in_sizes, int n_in,
                              void* d_out, int out_size, void* d_ws, size_t ws_size,
                              hipStream_t stream) {
  const float* xin   = (const float*)d_in[0];
  const int*   mask  = (const int*)d_in[1];
  const float* W0    = (const float*)d_in[2];
  const float* a0    = (const float*)d_in[3];
  const float* W1    = (const float*)d_in[4];
  const float* a1    = (const float*)d_in[5];
  const float* gamma = (const float*)d_in[6];
  const float* beta  = (const float*)d_in[7];

  ushort* xg0     = (ushort*)d_ws;                       // 8.39 MB compact bf16
  ushort* xg1     = xg0 + (size_t)BT * NN * FF;          // 8.39 MB compact bf16
  int*    rrank_g = (int*)(xg1 + (size_t)BT * NN * FF);  // 131 KB

  layer_kernel<true><<<BT * HH, 256, 0, stream>>>(xin, nullptr, mask, W0, a0, xg0, rrank_g);
  layer_kernel<false><<<BT * HH, 256, 0, stream>>>(nullptr, xg0, mask, W1, a1, xg1, nullptr);
  ln_scatter<<<BT * 4, 256, 0, stream>>>(xg1, rrank_g, gamma, beta, (float*)d_out);
}

// Round 8
// 43.637 us; speedup vs baseline: 6.1274x; 1.1045x over previous
//
#include <hip/hip_runtime.h>
#include <hip/hip_bf16.h>

#define BT 128   // B*T
#define NN 256   // nodes
#define FF 128   // features
#define HH 4     // heads
#define DD 32    // head dim
#define XK 136   // LDS k-stride (bf16): 272B, 16B-aligned
#define WCS 264  // LDS col-stride (bf16) for whc: 528B
#define L2E 1.4426950408889634f

typedef __attribute__((ext_vector_type(8))) short bf16x8;
typedef __attribute__((ext_vector_type(4))) float f32x4;
typedef unsigned int uint;
typedef unsigned short ushort;

__device__ __forceinline__ float elu1(float x) { return x > 0.f ? x : (__expf(x) - 1.f); }
__device__ __forceinline__ float exp2_fast(float x) {
  float r; asm("v_exp_f32 %0, %1" : "=v"(r) : "v"(x)); return r;
}
__device__ __forceinline__ ushort f2bfn(float f) {
  __hip_bfloat16 h = __float2bfloat16(f);
  return *reinterpret_cast<ushort*>(&h);
}
__device__ __forceinline__ float bf2f(ushort u) {
  union { uint u; float f; } v; v.u = ((uint)u) << 16; return v.f;
}
__device__ __forceinline__ uint pk2(float a, float b) {  // -> v_cvt_pk_bf16_f32
  return (uint)f2bfn(a) | ((uint)f2bfn(b) << 16);
}

// Block = (bt, head), 512 threads / 8 waves (4 waves/SIMD at 2 blocks/CU).
// A-fragments straight from global; scores fused into GEMM epilogue via
// butterfly shfl; rank-1 P in registers; PV MFMA; residual+ELU -> compact xg.
template<bool L0F>
__global__ __launch_bounds__(512, 2) void layer_kernel(
    const float* __restrict__ xin, const ushort* __restrict__ xprev,
    const int* __restrict__ mask, const float* __restrict__ W,
    const float* __restrict__ av, ushort* __restrict__ xg,
    int* __restrict__ rrank_g) {
  __shared__ __align__(16) ushort wt[DD * XK];    // 8.7 KB
  __shared__ __align__(16) ushort whc[DD * WCS];  // 16.9 KB
  __shared__ __align__(16) float s1s[NN];
  __shared__ __align__(16) float s2c[NN];
  __shared__ int jmap[NN];
  __shared__ int wcnt[4];

  const int bt = blockIdx.x >> 2;
  const int h = blockIdx.x & 3;
  const int tid = threadIdx.x;
  const int lane = tid & 63;
  const int w = tid >> 6;          // 0..7
  const int la = lane & 15, lg = lane >> 4;

  // ---- ballot compaction (tid < 256 only; mask is layer/head-invariant) ----
  if (tid < NN) {
    const int mv = mask[bt * NN + tid] > 0;
    unsigned long long bal = __ballot(mv);
    if (lane == 0) wcnt[w] = __popcll(bal);
    // rk computed after barrier (needs all wcnt)
  }
  __syncthreads();  // #1
  const int jv = wcnt[0] + wcnt[1] + wcnt[2] + wcnt[3];
  const int jv16 = (jv + 15) & ~15;
  const int ntiles = jv16 >> 4;
  const int jvp64 = (jv16 + 63) & ~63;
  const int njb = jvp64 >> 6;

  if (tid < NN) {
    const int mv = mask[bt * NN + tid] > 0;  // L2/L1-hot reload
    unsigned long long bal = __ballot(mv);
    int base = 0;
    #pragma unroll
    for (int ww = 0; ww < 4; ++ww) if (ww < w) base += wcnt[ww];
    const int rk = mv ? base + __popcll(bal & ((1ull << lane) - 1ull)) : -1;
    if (mv) jmap[rk] = tid;
    if (L0F && h == 0) rrank_g[bt * NN + tid] = rk;
    if (tid >= jv) { s2c[tid] = -2e9f; s1s[tid] = 0.f; }  // pads: p=0 exactly
    if (tid >= jv16 && tid < jvp64) {
      #pragma unroll
      for (int d = 0; d < DD; ++d) whc[d * WCS + tid] = 0;
    }
  }
  // stage wt[n][k] = W[k][h*32+n]: 512 threads, one pass, uint4 writes
  {
    const int n = tid & 31;
    const int k0 = (tid >> 5) * 8;  // 16 groups x 8 k
    float wv[8];
    #pragma unroll
    for (int p = 0; p < 8; ++p) wv[p] = W[(k0 + p) * FF + h * DD + n];
    uint4 q;
    q.x = pk2(wv[0], wv[1]); q.y = pk2(wv[2], wv[3]);
    q.z = pk2(wv[4], wv[5]); q.w = pk2(wv[6], wv[7]);
    *(uint4*)&wt[n * XK + k0] = q;
  }
  __syncthreads();  // #2: jmap, wt, pads ready

  bf16x8 bfr[2][4];
  #pragma unroll
  for (int ct = 0; ct < 2; ++ct)
    #pragma unroll
    for (int ks = 0; ks < 4; ++ks)
      bfr[ct][ks] = *(const bf16x8*)&wt[(ct * 16 + la) * XK + ks * 32 + lg * 8];
  const float a1a = av[la], a1b = av[16 + la];
  const float a2a = av[32 + la], a2b = av[48 + la];

  // ---- GEMM: per-wave 16-row tiles (8 waves), A direct from global ----
  for (int rt = w; rt < ntiles; rt += 8) {
    const int r = rt * 16 + la;
    const int src = (r < jv) ? (L0F ? jmap[r] : r) : 0;  // clamp: no OOB
    bf16x8 af[4];
    if (L0F) {
      const float* xp = xin + ((size_t)bt * NN + src) * FF;
      #pragma unroll
      for (int ks = 0; ks < 4; ++ks) {
        float4 v0 = *(const float4*)&xp[ks * 32 + lg * 8];
        float4 v1 = *(const float4*)&xp[ks * 32 + lg * 8 + 4];
        union { uint4 q; bf16x8 v; } u;
        u.q.x = pk2(v0.x, v0.y); u.q.y = pk2(v0.z, v0.w);
        u.q.z = pk2(v1.x, v1.y); u.q.w = pk2(v1.z, v1.w);
        af[ks] = u.v;
      }
    } else {
      const ushort* xp = xprev + ((size_t)bt * NN + src) * FF;
      #pragma unroll
      for (int ks = 0; ks < 4; ++ks)
        af[ks] = *(const bf16x8*)&xp[ks * 32 + lg * 8];
    }
    if (r >= jv) {  // zero pad rows -> whc pad cols exactly 0 (no NaN risk)
      bf16x8 zz = {0, 0, 0, 0, 0, 0, 0, 0};
      #pragma unroll
      for (int ks = 0; ks < 4; ++ks) af[ks] = zz;
    }
    f32x4 acc0 = {}, acc1 = {};
    #pragma unroll
    for (int ks = 0; ks < 4; ++ks) {
      acc0 = __builtin_amdgcn_mfma_f32_16x16x32_bf16(af[ks], bfr[0][ks], acc0, 0, 0, 0);
      acc1 = __builtin_amdgcn_mfma_f32_16x16x32_bf16(af[ks], bfr[1][ks], acc1, 0, 0, 0);
    }
    {
      uint2 pa, pb;
      pa.x = pk2(acc0[0], acc0[1]); pa.y = pk2(acc0[2], acc0[3]);
      pb.x = pk2(acc1[0], acc1[1]); pb.y = pk2(acc1[2], acc1[3]);
      *(uint2*)&whc[la * WCS + rt * 16 + lg * 4] = pa;
      *(uint2*)&whc[(16 + la) * WCS + rt * 16 + lg * 4] = pb;
    }
    // fp32 scores butterfly-reduced over the 16 la-lanes
    #pragma unroll
    for (int reg = 0; reg < 4; ++reg) {
      float sc1 = fmaf(acc0[reg], a1a, acc1[reg] * a1b);
      float sc2 = fmaf(acc0[reg], a2a, acc1[reg] * a2b);
      #pragma unroll
      for (int off = 1; off < 16; off <<= 1) {
        sc1 += __shfl_xor(sc1, off);
        sc2 += __shfl_xor(sc2, off);
      }
      if (la == reg) {
        const int c = rt * 16 + lg * 4 + reg;
        s1s[c] = sc1 * L2E;
        s2c[c] = (c < jv) ? sc2 * L2E : -2e9f;
      }
    }
  }
  __syncthreads();  // #3: whc, s1s, s2c complete

  // ---- s2max: per-wave reduce over all 256 entries (no extra barrier) ----
  float m = fmaxf(fmaxf(s2c[lane], s2c[64 + lane]),
                  fmaxf(s2c[128 + lane], s2c[192 + lane]));
  #pragma unroll
  for (int off = 32; off > 0; off >>= 1) m = fmaxf(m, __shfl_xor(m, off));
  const float s2max = m;

  // ---- PV: wave w owns tiles ti = mi*8 + w (mi < 2); P in registers ----
  float s1r[2], em[2];
  #pragma unroll
  for (int mi = 0; mi < 2; ++mi) {
    float s1v = s1s[((mi * 8 + w) * 16 + la) & 255];
    s1r[mi] = s1v;
    float t = s1v + s2max;
    em[mi] = fmaxf(t, 0.2f * t);  // exact row max (lrelu monotone)
  }
  f32x4 acc[2][2] = {};
  float den[2] = {0.f, 0.f};
  for (int jb = 0; jb < njb; ++jb) {
    #pragma unroll
    for (int ks = 0; ks < 2; ++ks) {
      const int j0 = jb * 64 + ks * 32 + lg * 8;
      float4 sa = *(const float4*)&s2c[j0];
      float4 sb = *(const float4*)&s2c[j0 + 4];
      bf16x8 b0 = *(const bf16x8*)&whc[la * WCS + j0];
      bf16x8 b1 = *(const bf16x8*)&whc[(16 + la) * WCS + j0];
      #pragma unroll
      for (int mi = 0; mi < 2; ++mi) {
        if (mi * 8 + w < ntiles) {  // wave-uniform
          const float s1v = s1r[mi], emv = em[mi];
          float t0 = s1v + sa.x, t1 = s1v + sa.y, t2 = s1v + sa.z, t3 = s1v + sa.w;
          float t4 = s1v + sb.x, t5 = s1v + sb.y, t6 = s1v + sb.z, t7 = s1v + sb.w;
          float p0 = exp2_fast(fmaxf(t0, 0.2f * t0) - emv);
          float p1 = exp2_fast(fmaxf(t1, 0.2f * t1) - emv);
          float p2 = exp2_fast(fmaxf(t2, 0.2f * t2) - emv);
          float p3 = exp2_fast(fmaxf(t3, 0.2f * t3) - emv);
          float p4 = exp2_fast(fmaxf(t4, 0.2f * t4) - emv);
          float p5 = exp2_fast(fmaxf(t5, 0.2f * t5) - emv);
          float p6 = exp2_fast(fmaxf(t6, 0.2f * t6) - emv);
          float p7 = exp2_fast(fmaxf(t7, 0.2f * t7) - emv);
          den[mi] += ((p0 + p1) + (p2 + p3)) + ((p4 + p5) + (p6 + p7));
          union { uint4 q; bf16x8 v; } u;
          u.q.x = pk2(p0, p1); u.q.y = pk2(p2, p3);
          u.q.z = pk2(p4, p5); u.q.w = pk2(p6, p7);
          acc[mi][0] = __builtin_amdgcn_mfma_f32_16x16x32_bf16(u.v, b0, acc[mi][0], 0, 0, 0);
          acc[mi][1] = __builtin_amdgcn_mfma_f32_16x16x32_bf16(u.v, b1, acc[mi][1], 0, 0, 0);
        }
      }
    }
  }
  #pragma unroll
  for (int mi = 0; mi < 2; ++mi) {
    den[mi] += __shfl_xor(den[mi], 16);
    den[mi] += __shfl_xor(den[mi], 32);
  }

  // ---- epilogue: residual + ELU -> compact bf16 xg ----
  #pragma unroll
  for (int mi = 0; mi < 2; ++mi) {
    const int ti = mi * 8 + w;
    if (ti < ntiles) {
      const float inv = 1.f / den[mi];  // valid row => p_self > 0
      #pragma unroll
      for (int reg = 0; reg < 4; ++reg) {
        const float invr = __shfl(inv, lg * 4 + reg);
        const int c2 = ti * 16 + lg * 4 + reg;
        if (c2 < jv) {
          #pragma unroll
          for (int nt = 0; nt < 2; ++nt) {
            const int f = h * DD + nt * 16 + la;
            float resid;
            if (L0F) resid = xin[((size_t)bt * NN + jmap[c2]) * FF + f];
            else     resid = bf2f(xprev[((size_t)bt * NN + c2) * FF + f]);
            float v = elu1(resid + acc[mi][nt][reg] * invr);
            xg[((size_t)bt * NN + c2) * FF + f] = f2bfn(v);
          }
        }
      }
    }
  }
}

// Block = (bt, node-quarter). 4 lanes per node row (32 features each).
__global__ __launch_bounds__(256) void ln_scatter(
    const ushort* __restrict__ xg1, const int* __restrict__ rrank_g,
    const float* __restrict__ gam, const float* __restrict__ bet,
    float* __restrict__ out) {
  const int bt = blockIdx.x >> 2;
  const int q = blockIdx.x & 3;
  const int node = q * 64 + (threadIdx.x >> 2);
  const int fb = (threadIdx.x & 3) * 32;
  const int rk = rrank_g[bt * NN + node];
  float* op = out + ((size_t)bt * NN + node) * FF + fb;
  if (rk < 0) {
    float4 z = {0.f, 0.f, 0.f, 0.f};
    #pragma unroll
    for (int i = 0; i < 8; ++i) *(float4*)&op[i * 4] = z;
  } else {
    const ushort* xr = xg1 + ((size_t)bt * NN + rk) * FF + fb;
    float f[32];
    #pragma unroll
    for (int i = 0; i < 4; ++i) {
      uint4 u = *(const uint4*)&xr[i * 8];
      const uint* pu = (const uint*)&u;
      #pragma unroll
      for (int e = 0; e < 4; ++e) {
        f[i * 8 + e * 2]     = bf2f((ushort)(pu[e] & 0xffffu));
        f[i * 8 + e * 2 + 1] = bf2f((ushort)(pu[e] >> 16));
      }
    }
    float sum = 0.f, sq = 0.f;
    #pragma unroll
    for (int i = 0; i < 32; ++i) { sum += f[i]; sq = fmaf(f[i], f[i], sq); }
    sum += __shfl_xor(sum, 1); sq += __shfl_xor(sq, 1);
    sum += __shfl_xor(sum, 2); sq += __shfl_xor(sq, 2);
    const float mu = sum * (1.f / FF);
    const float var = sq * (1.f / FF) - mu * mu;
    const float rstd = rsqrtf(var + 1e-5f);
    #pragma unroll
    for (int i = 0; i < 8; ++i) {
      float4 g = *(const float4*)&gam[fb + i * 4];
      float4 b = *(const float4*)&bet[fb + i * 4];
      float4 o;
      o.x = (f[i * 4]     - mu) * rstd * g.x + b.x;
      o.y = (f[i * 4 + 1] - mu) * rstd * g.y + b.y;
      o.z = (f[i * 4 + 2] - mu) * rstd * g.z + b.z;
      o.w = (f[i * 4 + 3] - mu) * rstd * g.w + b.w;
      *(float4*)&op[i * 4] = o;
    }
  }
}

extern "C" void kernel_launch(void* const* d_in, const int* in_sizes, int n_in,
                              void* d_out, int out_size, void* d_ws, size_t ws_size,
                              hipStream_t stream) {
  const float* xin   = (const float*)d_in[0];
  const int*   mask  = (const int*)d_in[1];
  const float* W0    = (const float*)d_in[2];
  const float* a0    = (const float*)d_in[3];
  const float* W1    = (const float*)d_in[4];
  const float* a1    = (const float*)d_in[5];
  const float* gamma = (const float*)d_in[6];
  const float* beta  = (const float*)d_in[7];

  ushort* xg0     = (ushort*)d_ws;                       // 8.39 MB compact bf16
  ushort* xg1     = xg0 + (size_t)BT * NN * FF;          // 8.39 MB compact bf16
  int*    rrank_g = (int*)(xg1 + (size_t)BT * NN * FF);  // 131 KB

  layer_kernel<true><<<BT * HH, 512, 0, stream>>>(xin, nullptr, mask, W0, a0, xg0, rrank_g);
  layer_kernel<false><<<BT * HH, 512, 0, stream>>>(nullptr, xg0, mask, W1, a1, xg1, nullptr);
  ln_scatter<<<BT * 4, 256, 0, stream>>>(xg1, rrank_g, gamma, beta, (float*)d_out);
}

// Round 9
// 41.501 us; speedup vs baseline: 6.4429x; 1.0515x over previous
//
#include <hip/hip_runtime.h>
#include <hip/hip_bf16.h>

#define BT 128   // B*T
#define NN 256   // nodes
#define FF 128   // features
#define HH 4     // heads
#define DD 32    // head dim
#define XK 136   // LDS k-stride (bf16): 272B, 16B-aligned
#define WCS 264  // LDS col-stride (bf16) for whc: 528B
#define L2E 1.4426950408889634f

typedef __attribute__((ext_vector_type(8))) short bf16x8;
typedef __attribute__((ext_vector_type(4))) float f32x4;
typedef unsigned int uint;
typedef unsigned short ushort;

__device__ __forceinline__ float elu1(float x) { return x > 0.f ? x : (__expf(x) - 1.f); }
__device__ __forceinline__ float exp2_fast(float x) {
  float r; asm("v_exp_f32 %0, %1" : "=v"(r) : "v"(x)); return r;
}
__device__ __forceinline__ ushort f2bfn(float f) {
  __hip_bfloat16 h = __float2bfloat16(f);
  return *reinterpret_cast<ushort*>(&h);
}
__device__ __forceinline__ float bf2f(ushort u) {
  union { uint u; float f; } v; v.u = ((uint)u) << 16; return v.f;
}
__device__ __forceinline__ uint pk2(float a, float b) {  // -> v_cvt_pk_bf16_f32
  return (uint)f2bfn(a) | ((uint)f2bfn(b) << 16);
}

// Block = (bt, head) with XCD-grouped decode: all 4 head-blocks of a bt land on
// the same XCD (b%8 == bt>>4) so the bt's x-slice is fetched once per XCD L2.
// 512 threads / 8 waves. Early-issued W/x/resid loads hide serialized latency.
template<bool L0F>
__global__ __launch_bounds__(512, 2) void layer_kernel(
    const float* __restrict__ xin, const ushort* __restrict__ xprev,
    const int* __restrict__ mask, const float* __restrict__ W,
    const float* __restrict__ av, ushort* __restrict__ xg,
    int* __restrict__ rrank_g) {
  __shared__ __align__(16) ushort wt[DD * XK];    // 8.7 KB
  __shared__ __align__(16) ushort whc[DD * WCS];  // 16.9 KB
  __shared__ __align__(16) float s1s[NN];
  __shared__ __align__(16) float s2c[NN];
  __shared__ int jmap[NN];
  __shared__ int wcnt[4];

  // XCD-grouped decode: b = (bt>>4) + 8*((bt&15) + 16*h)
  const int b = blockIdx.x;
  const int s = b >> 3;
  const int bt = (b & 7) * 16 + (s & 15);
  const int h = s >> 4;
  const int tid = threadIdx.x;
  const int lane = tid & 63;
  const int w = tid >> 6;          // 0..7
  const int la = lane & 15, lg = lane >> 4;

  // ---- early issue: W slice (always), x A-fragments (L1 only) ----
  float wv[8];
  {
    const int n = tid & 31;
    const int k0 = (tid >> 5) * 8;
    #pragma unroll
    for (int p = 0; p < 8; ++p) wv[p] = W[(k0 + p) * FF + h * DD + n];
  }
  bf16x8 af_pre[4];
  if (!L0F) {
    const ushort* xp = xprev + ((size_t)bt * NN + w * 16 + la) * FF;
    #pragma unroll
    for (int ks = 0; ks < 4; ++ks)
      af_pre[ks] = *(const bf16x8*)&xp[ks * 32 + lg * 8];  // rows>=jv discarded later
  }

  // ---- ballot compaction (tid < 256; mask is layer/head-invariant) ----
  if (tid < NN) {
    const int mv = mask[bt * NN + tid] > 0;
    unsigned long long bal = __ballot(mv);
    if (lane == 0) wcnt[w] = __popcll(bal);
  }
  // stage wt[n][k] = W[k][h*32+n] (loads already in flight)
  {
    const int n = tid & 31;
    const int k0 = (tid >> 5) * 8;
    uint4 q;
    q.x = pk2(wv[0], wv[1]); q.y = pk2(wv[2], wv[3]);
    q.z = pk2(wv[4], wv[5]); q.w = pk2(wv[6], wv[7]);
    *(uint4*)&wt[n * XK + k0] = q;
  }
  __syncthreads();  // #1: wcnt + wt ready
  const int jv = wcnt[0] + wcnt[1] + wcnt[2] + wcnt[3];
  const int jv16 = (jv + 15) & ~15;
  const int ntiles = jv16 >> 4;
  const int jvp64 = (jv16 + 63) & ~63;
  const int njb = jvp64 >> 6;

  if (tid < NN) {
    const int mv = mask[bt * NN + tid] > 0;  // L1-hot reload
    unsigned long long bal = __ballot(mv);
    int base = 0;
    #pragma unroll
    for (int ww = 0; ww < 4; ++ww) if (ww < w) base += wcnt[ww];
    const int rk = mv ? base + __popcll(bal & ((1ull << lane) - 1ull)) : -1;
    if (mv) jmap[rk] = tid;
    if (L0F && h == 0) rrank_g[bt * NN + tid] = rk;
    if (tid >= jv) { s2c[tid] = -2e9f; s1s[tid] = 0.f; }  // pads: p=0 exactly
    if (tid >= jv16 && tid < jvp64) {
      #pragma unroll
      for (int d = 0; d < DD; ++d) whc[d * WCS + tid] = 0;
    }
  }
  // B fragments from wt (ready since #1)
  bf16x8 bfr[2][4];
  #pragma unroll
  for (int ct = 0; ct < 2; ++ct)
    #pragma unroll
    for (int ks = 0; ks < 4; ++ks)
      bfr[ct][ks] = *(const bf16x8*)&wt[(ct * 16 + la) * XK + ks * 32 + lg * 8];
  const float a1a = av[la], a1b = av[16 + la];
  const float a2a = av[32 + la], a2b = av[48 + la];
  __syncthreads();  // #2: jmap + pads ready

  if (jv == 0) return;  // fully-masked slice: ln_scatter zero-fills via rrank

  // ---- resid prefetch (hidden under GEMM + PV) ----
  float rpre[2][2][4];
  #pragma unroll
  for (int mi = 0; mi < 2; ++mi) {
    const int ti = mi * 8 + w;
    #pragma unroll
    for (int reg = 0; reg < 4; ++reg) {
      const int c2 = ti * 16 + lg * 4 + reg;
      const int ok = (ti < ntiles) && (c2 < jv);
      const int srow = ok ? (L0F ? jmap[c2] : c2) : (L0F ? jmap[0] : 0);
      #pragma unroll
      for (int nt = 0; nt < 2; ++nt) {
        const int f = h * DD + nt * 16 + la;
        rpre[mi][nt][reg] = L0F ? xin[((size_t)bt * NN + srow) * FF + f]
                                : bf2f(xprev[((size_t)bt * NN + srow) * FF + f]);
      }
    }
  }

  // ---- GEMM: per-wave 16-row tiles, A direct from global, fused scores ----
  for (int rt = w; rt < ntiles; rt += 8) {
    const int r = rt * 16 + la;
    const int src = (r < jv) ? (L0F ? jmap[r] : r) : 0;  // clamp: no OOB
    bf16x8 af[4];
    if (L0F) {
      const float* xp = xin + ((size_t)bt * NN + src) * FF;
      #pragma unroll
      for (int ks = 0; ks < 4; ++ks) {
        float4 v0 = *(const float4*)&xp[ks * 32 + lg * 8];
        float4 v1 = *(const float4*)&xp[ks * 32 + lg * 8 + 4];
        union { uint4 q; bf16x8 v; } u;
        u.q.x = pk2(v0.x, v0.y); u.q.y = pk2(v0.z, v0.w);
        u.q.z = pk2(v1.x, v1.y); u.q.w = pk2(v1.z, v1.w);
        af[ks] = u.v;
      }
    } else if (rt == w) {
      #pragma unroll
      for (int ks = 0; ks < 4; ++ks) af[ks] = af_pre[ks];
    } else {
      const ushort* xp = xprev + ((size_t)bt * NN + src) * FF;
      #pragma unroll
      for (int ks = 0; ks < 4; ++ks)
        af[ks] = *(const bf16x8*)&xp[ks * 32 + lg * 8];
    }
    if (r >= jv) {  // zero pad rows -> whc pad cols exactly 0 (no NaN risk)
      bf16x8 zz = {0, 0, 0, 0, 0, 0, 0, 0};
      #pragma unroll
      for (int ks = 0; ks < 4; ++ks) af[ks] = zz;
    }
    f32x4 acc0 = {}, acc1 = {};
    #pragma unroll
    for (int ks = 0; ks < 4; ++ks) {
      acc0 = __builtin_amdgcn_mfma_f32_16x16x32_bf16(af[ks], bfr[0][ks], acc0, 0, 0, 0);
      acc1 = __builtin_amdgcn_mfma_f32_16x16x32_bf16(af[ks], bfr[1][ks], acc1, 0, 0, 0);
    }
    {
      uint2 pa, pb;
      pa.x = pk2(acc0[0], acc0[1]); pa.y = pk2(acc0[2], acc0[3]);
      pb.x = pk2(acc1[0], acc1[1]); pb.y = pk2(acc1[2], acc1[3]);
      *(uint2*)&whc[la * WCS + rt * 16 + lg * 4] = pa;
      *(uint2*)&whc[(16 + la) * WCS + rt * 16 + lg * 4] = pb;
    }
    // fp32 scores butterfly-reduced over the 16 la-lanes
    #pragma unroll
    for (int reg = 0; reg < 4; ++reg) {
      float sc1 = fmaf(acc0[reg], a1a, acc1[reg] * a1b);
      float sc2 = fmaf(acc0[reg], a2a, acc1[reg] * a2b);
      #pragma unroll
      for (int off = 1; off < 16; off <<= 1) {
        sc1 += __shfl_xor(sc1, off);
        sc2 += __shfl_xor(sc2, off);
      }
      if (la == reg) {
        const int c = rt * 16 + lg * 4 + reg;
        s1s[c] = sc1 * L2E;
        s2c[c] = (c < jv) ? sc2 * L2E : -2e9f;
      }
    }
  }
  __syncthreads();  // #3: whc, s1s, s2c complete

  // ---- s2max: per-wave reduce over all 256 entries ----
  float m = fmaxf(fmaxf(s2c[lane], s2c[64 + lane]),
                  fmaxf(s2c[128 + lane], s2c[192 + lane]));
  #pragma unroll
  for (int off = 32; off > 0; off >>= 1) m = fmaxf(m, __shfl_xor(m, off));
  const float s2max = m;

  // ---- PV: wave w owns tiles ti = mi*8 + w (mi < 2); P in registers ----
  float s1r[2], em[2];
  #pragma unroll
  for (int mi = 0; mi < 2; ++mi) {
    float s1v = s1s[((mi * 8 + w) * 16 + la) & 255];
    s1r[mi] = s1v;
    float t = s1v + s2max;
    em[mi] = fmaxf(t, 0.2f * t);  // exact row max (lrelu monotone)
  }
  f32x4 acc[2][2] = {};
  float den[2] = {0.f, 0.f};
  for (int jb = 0; jb < njb; ++jb) {
    #pragma unroll
    for (int ks = 0; ks < 2; ++ks) {
      const int j0 = jb * 64 + ks * 32 + lg * 8;
      float4 sa = *(const float4*)&s2c[j0];
      float4 sb = *(const float4*)&s2c[j0 + 4];
      bf16x8 b0 = *(const bf16x8*)&whc[la * WCS + j0];
      bf16x8 b1 = *(const bf16x8*)&whc[(16 + la) * WCS + j0];
      #pragma unroll
      for (int mi = 0; mi < 2; ++mi) {
        if (mi * 8 + w < ntiles) {  // wave-uniform
          const float s1v = s1r[mi], emv = em[mi];
          float t0 = s1v + sa.x, t1 = s1v + sa.y, t2 = s1v + sa.z, t3 = s1v + sa.w;
          float t4 = s1v + sb.x, t5 = s1v + sb.y, t6 = s1v + sb.z, t7 = s1v + sb.w;
          float p0 = exp2_fast(fmaxf(t0, 0.2f * t0) - emv);
          float p1 = exp2_fast(fmaxf(t1, 0.2f * t1) - emv);
          float p2 = exp2_fast(fmaxf(t2, 0.2f * t2) - emv);
          float p3 = exp2_fast(fmaxf(t3, 0.2f * t3) - emv);
          float p4 = exp2_fast(fmaxf(t4, 0.2f * t4) - emv);
          float p5 = exp2_fast(fmaxf(t5, 0.2f * t5) - emv);
          float p6 = exp2_fast(fmaxf(t6, 0.2f * t6) - emv);
          float p7 = exp2_fast(fmaxf(t7, 0.2f * t7) - emv);
          den[mi] += ((p0 + p1) + (p2 + p3)) + ((p4 + p5) + (p6 + p7));
          union { uint4 q; bf16x8 v; } u;
          u.q.x = pk2(p0, p1); u.q.y = pk2(p2, p3);
          u.q.z = pk2(p4, p5); u.q.w = pk2(p6, p7);
          acc[mi][0] = __builtin_amdgcn_mfma_f32_16x16x32_bf16(u.v, b0, acc[mi][0], 0, 0, 0);
          acc[mi][1] = __builtin_amdgcn_mfma_f32_16x16x32_bf16(u.v, b1, acc[mi][1], 0, 0, 0);
        }
      }
    }
  }
  #pragma unroll
  for (int mi = 0; mi < 2; ++mi) {
    den[mi] += __shfl_xor(den[mi], 16);
    den[mi] += __shfl_xor(den[mi], 32);
  }

  // ---- epilogue: residual (prefetched) + ELU -> compact bf16 xg ----
  #pragma unroll
  for (int mi = 0; mi < 2; ++mi) {
    const int ti = mi * 8 + w;
    if (ti < ntiles) {
      const float inv = 1.f / den[mi];  // valid row => p_self > 0
      #pragma unroll
      for (int reg = 0; reg < 4; ++reg) {
        const float invr = __shfl(inv, lg * 4 + reg);
        const int c2 = ti * 16 + lg * 4 + reg;
        if (c2 < jv) {
          #pragma unroll
          for (int nt = 0; nt < 2; ++nt) {
            const int f = h * DD + nt * 16 + la;
            float v = elu1(rpre[mi][nt][reg] + acc[mi][nt][reg] * invr);
            xg[((size_t)bt * NN + c2) * FF + f] = f2bfn(v);
          }
        }
      }
    }
  }
}

// Block = (bt, node-quarter), XCD-grouped same as layer (b%8 == bt>>4).
__global__ __launch_bounds__(256) void ln_scatter(
    const ushort* __restrict__ xg1, const int* __restrict__ rrank_g,
    const float* __restrict__ gam, const float* __restrict__ bet,
    float* __restrict__ out) {
  const int b = blockIdx.x;
  const int bt = (b & 7) * 16 + ((b >> 3) & 15);
  const int q = b >> 7;
  const int node = q * 64 + (threadIdx.x >> 2);
  const int fb = (threadIdx.x & 3) * 32;
  const int rk = rrank_g[bt * NN + node];
  float* op = out + ((size_t)bt * NN + node) * FF + fb;
  if (rk < 0) {
    float4 z = {0.f, 0.f, 0.f, 0.f};
    #pragma unroll
    for (int i = 0; i < 8; ++i) *(float4*)&op[i * 4] = z;
  } else {
    const ushort* xr = xg1 + ((size_t)bt * NN + rk) * FF + fb;
    float f[32];
    #pragma unroll
    for (int i = 0; i < 4; ++i) {
      uint4 u = *(const uint4*)&xr[i * 8];
      const uint* pu = (const uint*)&u;
      #pragma unroll
      for (int e = 0; e < 4; ++e) {
        f[i * 8 + e * 2]     = bf2f((ushort)(pu[e] & 0xffffu));
        f[i * 8 + e * 2 + 1] = bf2f((ushort)(pu[e] >> 16));
      }
    }
    float sum = 0.f, sq = 0.f;
    #pragma unroll
    for (int i = 0; i < 32; ++i) { sum += f[i]; sq = fmaf(f[i], f[i], sq); }
    sum += __shfl_xor(sum, 1); sq += __shfl_xor(sq, 1);
    sum += __shfl_xor(sum, 2); sq += __shfl_xor(sq, 2);
    const float mu = sum * (1.f / FF);
    const float var = sq * (1.f / FF) - mu * mu;
    const float rstd = rsqrtf(var + 1e-5f);
    #pragma unroll
    for (int i = 0; i < 8; ++i) {
      float4 g = *(const float4*)&gam[fb + i * 4];
      float4 bb = *(const float4*)&bet[fb + i * 4];
      float4 o;
      o.x = (f[i * 4]     - mu) * rstd * g.x + bb.x;
      o.y = (f[i * 4 + 1] - mu) * rstd * g.y + bb.y;
      o.z = (f[i * 4 + 2] - mu) * rstd * g.z + bb.z;
      o.w = (f[i * 4 + 3] - mu) * rstd * g.w + bb.w;
      *(float4*)&op[i * 4] = o;
    }
  }
}

extern "C" void kernel_launch(void* const* d_in, const int* in_sizes, int n_in,
                              void* d_out, int out_size, void* d_ws, size_t ws_size,
                              hipStream_t stream) {
  const float* xin   = (const float*)d_in[0];
  const int*   mask  = (const int*)d_in[1];
  const float* W0    = (const float*)d_in[2];
  const float* a0    = (const float*)d_in[3];
  const float* W1    = (const float*)d_in[4];
  const float* a1    = (const float*)d_in[5];
  const float* gamma = (const float*)d_in[6];
  const float* beta  = (const float*)d_in[7];

  ushort* xg0     = (ushort*)d_ws;                       // 8.39 MB compact bf16
  ushort* xg1     = xg0 + (size_t)BT * NN * FF;          // 8.39 MB compact bf16
  int*    rrank_g = (int*)(xg1 + (size_t)BT * NN * FF);  // 131 KB

  layer_kernel<true><<<BT * HH, 512, 0, stream>>>(xin, nullptr, mask, W0, a0, xg0, rrank_g);
  layer_kernel<false><<<BT * HH, 512, 0, stream>>>(nullptr, xg0, mask, W1, a1, xg1, nullptr);
  ln_scatter<<<BT * 4, 256, 0, stream>>>(xg1, rrank_g, gamma, beta, (float*)d_out);
}